// Round 16
// baseline (165.792 us; speedup 1.0000x reference)
//
#include <hip/hip_runtime.h>
#include <hip/hip_bf16.h>

#define NN      150000
#define NUSERS  50000
#define DD      128
#define EE      500000
#define BB      16384
#define NSLICE  32           // BN-stats atomic slices
#define ESTRIDE 32           // fixed edge slots per destination row

using short8  = __attribute__((ext_vector_type(8))) short;
using ushort8 = __attribute__((ext_vector_type(8))) unsigned short;
using f32x4   = __attribute__((ext_vector_type(4))) float;

typedef __attribute__((address_space(1))) const unsigned int glb_u32;
typedef __attribute__((address_space(3))) unsigned int       lds_u32;

__device__ __forceinline__ short f2bf(float v) {
    __hip_bfloat16 b = __float2bfloat16(v);      // RNE; pairs fuse to v_cvt_pk_bf16_f32
    return __builtin_bit_cast(short, b);
}
__device__ __forceinline__ float bf2f(unsigned short b) {
    return __uint_as_float(((unsigned)b) << 16);
}

// ---------------- prep: zero scratch + build W fragments (fused) ------------
__global__ __launch_bounds__(256) void prep_k(int4* __restrict__ zbase, int zn4, int zb,
                                              const float* __restrict__ W1,
                                              const float* __restrict__ W2,
                                              short* __restrict__ F1,
                                              short* __restrict__ F2) {
    int b = blockIdx.x;
    if (b < zb) {
        int i = b * 256 + threadIdx.x;
        if (i < zn4) zbase[i] = make_int4(0, 0, 0, 0);
        return;
    }
    int idx = (b - zb) * 256 + threadIdx.x;     // [0, 32768)
    int m = idx >> 14;
    int i = idx & 16383;
    int e  = i & 7;
    int l  = (i >> 3) & 63;
    int kk = (i >> 9) & 3;
    int ct = i >> 11;
    int k = kk * 32 + (l >> 4) * 8 + e;
    int c = ct * 16 + (l & 15);
    const float* W = m ? W2 : W1;
    short*       F = m ? F2 : F1;
    F[i] = f2bf(W[k * DD + c]);
}

// ---------------- fused degree count + strided edge fill + rated bitmap -----
__global__ __launch_bounds__(256) void countfill_k(const int* __restrict__ src,
                                                   const int* __restrict__ dst,
                                                   int* __restrict__ cnt,
                                                   int* __restrict__ sedge,
                                                   const int* __restrict__ srcn,
                                                   const int* __restrict__ dstn,
                                                   unsigned char* __restrict__ flags) {
    int e = blockIdx.x * 256 + threadIdx.x;
    if (e < EE) {
        int d = dst[e], s = src[e];
        int pos = atomicAdd(&cnt[d], 1);
        if (pos > ESTRIDE - 1) pos = ESTRIDE - 1;      // safety clamp (max deg ~16)
        sedge[(size_t)d * ESTRIDE + pos] = s;
    }
    if (e < BB) { flags[srcn[e]] = 1; flags[dstn[e]] = 1; }
}

// ---------------- dis table: dis[i] = rsqrt(cnt[i]+1) ----------------
__global__ __launch_bounds__(256) void dis_k(const int* __restrict__ cnt,
                                             float* __restrict__ dis) {
    int i = blockIdx.x * 256 + threadIdx.x;
    if (i < NN) dis[i] = rsqrtf((float)cnt[i] + 1.0f);
}

// ---------------- MFMA GEMM v8: Wfrag in LDS, PRE-SCALED output -------------
// MODE 0: A = concat(A0[0:nsplit], A1) fp32, raw.            Layer 1.
// MODE 1: A = relu(bf16(Ab) * coefs[c] + coefs[128+c]).      Layer 2.
// Writes hs[i] = dis[i] * (A@W)[i]  (bf16).  Gather then needs NO per-edge
// weights: agg[i] = dis[i] * (sum_{s in N(i)} hs[s] + hs[i]).
template<int MODE>
__global__ __launch_bounds__(256) void gemm_mfma_k(const float* __restrict__ A0,
                                                   const float* __restrict__ A1,
                                                   int nsplit,
                                                   const unsigned short* __restrict__ Ab,
                                                   const float* __restrict__ coefs,
                                                   const short* __restrict__ Wfrag,
                                                   const float* __restrict__ disv,
                                                   unsigned short* __restrict__ hout) {
    __shared__ __align__(16) char smem[32768];       // full Wfrag

    int t    = threadIdx.x;
    int wave = t >> 6;           // 0..3
    int lane = t & 63;
    int kgrp = lane >> 4;        // 0..3
    int lrow = lane & 15;

    // ---- stage Wfrag into LDS (8 x 256 x 16B = 32KB, linear) ----
#pragma unroll
    for (int r = 0; r < 8; ++r) {
        const char* src = (const char*)Wfrag + (r * 256 + t) * 16;
        lds_u32* dst = (lds_u32*)(smem + (r * 256 + wave * 64) * 16);  // wave-uniform base
        __builtin_amdgcn_global_load_lds((glb_u32*)src, dst, 16, 0, 0);
    }

    // ---- A-row pointer (direct global) ----
    int row = blockIdx.x * 64 + wave * 16 + lrow;
    int lr = row > NN - 1 ? NN - 1 : row;
    const float* arow = nullptr;
    const unsigned short* brow = nullptr;
    if (MODE == 0) arow = (lr < nsplit) ? A0 + (size_t)lr * DD
                                        : A1 + (size_t)(lr - nsplit) * DD;
    else           brow = Ab + (size_t)lr * DD;
    float dv = disv[lr];

    f32x4 acc[8];
#pragma unroll
    for (int ct = 0; ct < 8; ++ct) acc[ct] = (f32x4){0.f, 0.f, 0.f, 0.f};

    __syncthreads();   // Wfrag staged (drains vmcnt(0))

    const short8* wf = (const short8*)smem;

#pragma unroll
    for (int kk = 0; kk < 4; ++kk) {
        int d0 = kk * 32 + kgrp * 8;
        short8 rfrag;
        if (MODE == 0) {
            f32x4 va = *(const f32x4*)(arow + d0);
            f32x4 vb = *(const f32x4*)(arow + d0 + 4);
#pragma unroll
            for (int j = 0; j < 4; ++j) { rfrag[j] = f2bf(va[j]); rfrag[4 + j] = f2bf(vb[j]); }
        } else {
            ushort8 u = *(const ushort8*)(brow + d0);
            f32x4 s1 = *(const f32x4*)(coefs + d0);
            f32x4 s2 = *(const f32x4*)(coefs + d0 + 4);
            f32x4 t1 = *(const f32x4*)(coefs + 128 + d0);
            f32x4 t2 = *(const f32x4*)(coefs + 128 + d0 + 4);
#pragma unroll
            for (int j = 0; j < 4; ++j) {
                rfrag[j]     = f2bf(fmaxf(bf2f(u[j])     * s1[j] + t1[j], 0.f));
                rfrag[4 + j] = f2bf(fmaxf(bf2f(u[4 + j]) * s2[j] + t2[j], 0.f));
            }
        }
#pragma unroll
        for (int ct = 0; ct < 8; ++ct) {
            short8 wfr = wf[(ct * 4 + kk) * 64 + lane];   // contiguous ds_read_b128
            acc[ct] = __builtin_amdgcn_mfma_f32_16x16x32_bf16(wfr, rfrag, acc[ct], 0, 0, 0);
        }
    }

    // D layout (swapped operands): lane holds row fixed, cols ct*16+kgrp*4+j.
    // Pre-scale by dis[row] before bf16 pack.
    if (row < NN) {
        size_t rb = (size_t)row * DD;
#pragma unroll
        for (int ct = 0; ct < 8; ++ct) {
            int col = ct * 16 + kgrp * 4;
            unsigned p0 = (unsigned)(unsigned short)f2bf(acc[ct][0] * dv)
                        | ((unsigned)(unsigned short)f2bf(acc[ct][1] * dv) << 16);
            unsigned p1 = (unsigned)(unsigned short)f2bf(acc[ct][2] * dv)
                        | ((unsigned)(unsigned short)f2bf(acc[ct][3] * dv) << 16);
            uint2 p; p.x = p0; p.y = p1;
            *(uint2*)(hout + rb + col) = p;
        }
    }
}

// ---------------- unweighted gather + fused BN stats ----------------
// agg[i] = dis[i] * (sum_{s in N(i)} hs[s] + hs[i]) — hs is pre-scaled, so the
// inner loop is a plain sum: no per-edge weight loads. Tail dups masked with
// 0/1 FMA (same VALU rate as add). Stats LDS tile [16][129]: odd stride, ~2-way.
// PRUNE=1: store agg row only if flags[row] (rated); stats always from regs.
template<int PRUNE>
__global__ __launch_bounds__(256) void gather_k(const unsigned short* __restrict__ h,
                                                const int* __restrict__ sedge,
                                                const int* __restrict__ cnt,
                                                const float* __restrict__ dis,
                                                const unsigned char* __restrict__ flags,
                                                unsigned short* __restrict__ aggb,
                                                float* __restrict__ sums) {
    int t = threadIdx.x;
    int l = t & 15;                       // col octet index (8 cols each)
    int rg = t >> 4;                      // row within block
    int row = blockIdx.x * 16 + rg;
    int len = min(cnt[row], ESTRIDE);
    const int* se = sedge + (size_t)row * ESTRIDE;
    const ushort8* hp = (const ushort8*)h;

    float acc[8];
#pragma unroll
    for (int j = 0; j < 8; ++j) acc[j] = 0.f;

    for (int base = 0; base < len; base += 4) {
        int i1 = min(base + 1, len - 1);
        int i2 = min(base + 2, len - 1);
        int i3 = min(base + 3, len - 1);
        int s0 = se[base], s1 = se[i1], s2 = se[i2], s3 = se[i3];
        ushort8 h0 = hp[(size_t)s0 * 16 + l];
        ushort8 h1 = hp[(size_t)s1 * 16 + l];
        ushort8 h2 = hp[(size_t)s2 * 16 + l];
        ushort8 h3 = hp[(size_t)s3 * 16 + l];
        float w1 = (base + 1 < len) ? 1.f : 0.f;     // tail-dup masks
        float w2 = (base + 2 < len) ? 1.f : 0.f;
        float w3 = (base + 3 < len) ? 1.f : 0.f;
#pragma unroll
        for (int j = 0; j < 8; ++j) {
            acc[j] += bf2f(h0[j]) + w1 * bf2f(h1[j])
                    + w2 * bf2f(h2[j]) + w3 * bf2f(h3[j]);
        }
    }
    float d = dis[row];
    ushort8 hs = hp[(size_t)row * 16 + l];
    float r[8];
    ushort8 o;
#pragma unroll
    for (int j = 0; j < 8; ++j) {
        r[j] = d * (acc[j] + bf2f(hs[j]));
        o[j] = (unsigned short)f2bf(r[j]);
    }
    if (!PRUNE || flags[row])
        ((ushort8*)aggb)[(size_t)row * 16 + l] = o;

    // fused BN stats: block-local column reduction (odd stride), atomics
    __shared__ float red[16][129];
    float* slice = sums + (blockIdx.x & (NSLICE - 1)) * 256;
    int co = l * 8;
#pragma unroll
    for (int j = 0; j < 8; ++j) red[rg][co + j] = r[j];
    __syncthreads();
    if (t < 128) {
        float a = 0.f;
#pragma unroll
        for (int g = 0; g < 16; ++g) a += red[g][t];
        atomicAdd(&slice[t], a);
    }
    __syncthreads();
#pragma unroll
    for (int j = 0; j < 8; ++j) red[rg][co + j] = r[j] * r[j];
    __syncthreads();
    if (t < 128) {
        float a = 0.f;
#pragma unroll
        for (int g = 0; g < 16; ++g) a += red[g][t];
        atomicAdd(&slice[128 + t], a);
    }
}

// ---------------- BN coefficients (reduce NSLICE slices) ----------------
__global__ void bncoef_k(const float* __restrict__ sums,
                         const float* __restrict__ gamma,
                         const float* __restrict__ beta,
                         float* __restrict__ coefs) {
    int c = threadIdx.x;
    if (c >= DD) return;
    float s = 0.f, s2 = 0.f;
#pragma unroll
    for (int g = 0; g < NSLICE; ++g) {
        s  += sums[g * 256 + c];
        s2 += sums[g * 256 + 128 + c];
    }
    const float n = (float)NN;
    float m  = s / n;
    float v  = s2 / n - m * m;
    float is = rsqrtf(v + 1e-5f);
    float sc = gamma[c] * is;
    coefs[c] = sc;
    coefs[128 + c] = beta[c] - m * sc;
}

// ---------------- ratings: wave per pair, BN2+relu inline (bf16 x) ----------
__global__ __launch_bounds__(256) void ratings_k(const unsigned short* __restrict__ x,
                                                 const int* __restrict__ srcn,
                                                 const int* __restrict__ dstn,
                                                 const float* __restrict__ coefs,
                                                 float* __restrict__ out) {
    int wid  = (blockIdx.x * 256 + threadIdx.x) >> 6;
    int lane = threadIdx.x & 63;
    if (wid >= BB) return;
    int u = srcn[wid], v = dstn[wid];
    const ushort2* xp = (const ushort2*)x;
    ushort2 a = xp[(size_t)u * 64 + lane];
    ushort2 b = xp[(size_t)v * 64 + lane];
    float2 sc = ((const float2*)coefs)[lane];
    float2 sh = ((const float2*)(coefs + 128))[lane];
    float ax = fmaxf(bf2f(a.x) * sc.x + sh.x, 0.f);
    float ay = fmaxf(bf2f(a.y) * sc.y + sh.y, 0.f);
    float bx = fmaxf(bf2f(b.x) * sc.x + sh.x, 0.f);
    float by = fmaxf(bf2f(b.y) * sc.y + sh.y, 0.f);
    float acc = ax * bx + ay * by;
#pragma unroll
    for (int off = 32; off; off >>= 1) acc += __shfl_down(acc, off, 64);
    if (lane == 0) out[wid] = acc;
}

extern "C" void kernel_launch(void* const* d_in, const int* in_sizes, int n_in,
                              void* d_out, int out_size, void* d_ws, size_t ws_size,
                              hipStream_t stream) {
    const int*   edge  = (const int*)d_in[0];      // [2,E]
    const int*   esrc  = edge;
    const int*   edst  = edge + EE;
    const int*   srcn  = (const int*)d_in[2];
    const int*   dstn  = (const int*)d_in[3];
    const float* uemb  = (const float*)d_in[4];
    const float* bemb  = (const float*)d_in[5];
    const float* W1    = (const float*)d_in[6];
    // b1 = d_in[7]  (per-column constant, cancels in BN)
    const float* g1    = (const float*)d_in[8];
    const float* be1   = (const float*)d_in[9];
    const float* W2    = (const float*)d_in[10];
    // b2 = d_in[11] (cancels in BN)
    const float* g2    = (const float*)d_in[12];
    const float* be2   = (const float*)d_in[13];
    float* out = (float*)d_out;

    // workspace layout (16B-aligned; NN padded to 150016).
    // Zeroed range (contiguous): cnt, flags, sums1, sums2. dis fully written by dis_k.
    unsigned short* aggb   = (unsigned short*)d_ws;                      // N*D bf16
    unsigned short* hbuf   = aggb + (size_t)NN * DD;                     // N*D bf16 (pre-scaled hs)
    int*            cnt    = (int*)(hbuf + (size_t)NN * DD);             // 150016
    unsigned char*  flags  = (unsigned char*)(cnt + 150016);             // 150016 bytes
    float*          sums1  = (float*)(flags + 150016);                   // NSLICE*256
    float*          sums2  = sums1 + NSLICE * 256;                       // NSLICE*256
    float*          dis    = sums2 + NSLICE * 256;                       // 150016
    int*            sedge  = (int*)(dis + 150016);                       // 150016*32 int (19.2MB)
    short*          Wf1    = (short*)(sedge + (size_t)150016 * ESTRIDE); // 16384 bf16
    short*          Wf2    = Wf1 + 16384;                                // 16384 bf16
    float*          coef1  = (float*)(Wf2 + 16384);                      // 256
    float*          coef2  = coef1 + 256;                                // 256

    const int zn4   = (150016 * 4 + 150016 + 2 * NSLICE * 256 * 4) / 16; // 50976 int4
    const int zb    = (zn4 + 255) / 256;           // 200 zero blocks
    const int egrid = (EE + 255) / 256;            // 1954
    const int ngrid = (NN + 255) / 256;            // 586
    const int ggrid = (NN + 63) / 64;              // 2344 MFMA-GEMM blocks (64 rows, 256 thr)
    const int agrid = NN / 16;                     // 9375 gather blocks (exactly full)

    // ---- build: zero + Wfrag, fused count+fill+bitmap, dis table ----
    prep_k<<<zb + 128, 256, 0, stream>>>((int4*)cnt, zn4, zb, W1, W2, Wf1, Wf2);
    countfill_k<<<egrid, 256, 0, stream>>>(esrc, edst, cnt, sedge, srcn, dstn, flags);
    dis_k<<<ngrid, 256, 0, stream>>>(cnt, dis);

    // ---- layer 1 ----
    gemm_mfma_k<0><<<ggrid, 256, 0, stream>>>(uemb, bemb, NUSERS, nullptr, nullptr, Wf1, dis, hbuf);
    gather_k<0><<<agrid, 256, 0, stream>>>(hbuf, sedge, cnt, dis, flags, aggb, sums1);
    bncoef_k<<<1, 128, 0, stream>>>(sums1, g1, be1, coef1);

    // ---- layer 2 (BN1+relu fused into GEMM A-load, bf16 A) ----
    gemm_mfma_k<1><<<ggrid, 256, 0, stream>>>(nullptr, nullptr, 0, aggb, coef1, Wf2, dis, hbuf);
    gather_k<1><<<agrid, 256, 0, stream>>>(hbuf, sedge, cnt, dis, flags, aggb, sums2);
    bncoef_k<<<1, 128, 0, stream>>>(sums2, g2, be2, coef2);

    // ---- ratings (BN2+relu inline) ----
    ratings_k<<<BB / 4, 256, 0, stream>>>(aggb, srcn, dstn, coef2, out);
}

// Round 17
// 157.562 us; speedup vs baseline: 1.0522x; 1.0522x over previous
//
#include <hip/hip_runtime.h>
#include <hip/hip_bf16.h>

#define NN      150000
#define NUSERS  50000
#define DD      128
#define EE      500000
#define BB      16384
#define NSLICE  32           // BN-stats atomic slices
#define ESTRIDE 16           // fixed edge slots per destination row (64B line)

using short8  = __attribute__((ext_vector_type(8))) short;
using ushort8 = __attribute__((ext_vector_type(8))) unsigned short;
using f32x4   = __attribute__((ext_vector_type(4))) float;

typedef __attribute__((address_space(1))) const unsigned int glb_u32;
typedef __attribute__((address_space(3))) unsigned int       lds_u32;

__device__ __forceinline__ short f2bf(float v) {
    __hip_bfloat16 b = __float2bfloat16(v);      // RNE; pairs fuse to v_cvt_pk_bf16_f32
    return __builtin_bit_cast(short, b);
}
__device__ __forceinline__ float bf2f(unsigned short b) {
    return __uint_as_float(((unsigned)b) << 16);
}

// ---------------- prep: zero scratch + build W fragments (fused) ------------
__global__ __launch_bounds__(256) void prep_k(int4* __restrict__ zbase, int zn4, int zb,
                                              const float* __restrict__ W1,
                                              const float* __restrict__ W2,
                                              short* __restrict__ F1,
                                              short* __restrict__ F2) {
    int b = blockIdx.x;
    if (b < zb) {
        int i = b * 256 + threadIdx.x;
        if (i < zn4) zbase[i] = make_int4(0, 0, 0, 0);
        return;
    }
    int idx = (b - zb) * 256 + threadIdx.x;     // [0, 32768)
    int m = idx >> 14;
    int i = idx & 16383;
    int e  = i & 7;
    int l  = (i >> 3) & 63;
    int kk = (i >> 9) & 3;
    int ct = i >> 11;
    int k = kk * 32 + (l >> 4) * 8 + e;
    int c = ct * 16 + (l & 15);
    const float* W = m ? W2 : W1;
    short*       F = m ? F2 : F1;
    F[i] = f2bf(W[k * DD + c]);
}

// ---------------- fused degree count + strided edge fill + rated bitmap -----
__global__ __launch_bounds__(256) void countfill_k(const int* __restrict__ src,
                                                   const int* __restrict__ dst,
                                                   int* __restrict__ cnt,
                                                   int* __restrict__ sedge,
                                                   const int* __restrict__ srcn,
                                                   const int* __restrict__ dstn,
                                                   unsigned char* __restrict__ flags) {
    int e = blockIdx.x * 256 + threadIdx.x;
    if (e < EE) {
        int d = dst[e], s = src[e];
        int pos = atomicAdd(&cnt[d], 1);
        if (pos > ESTRIDE - 1) pos = ESTRIDE - 1;      // safety clamp (max deg ~14-16)
        sedge[(size_t)d * ESTRIDE + pos] = s;
    }
    if (e < BB) { flags[srcn[e]] = 1; flags[dstn[e]] = 1; }
}

// ---------------- MFMA GEMM v8: Wfrag in LDS, PRE-SCALED output -------------
// MODE 0: A = concat(A0[0:nsplit], A1) fp32, raw.            Layer 1.
// MODE 1: A = relu(bf16(Ab) * coefs[c] + coefs[128+c]).      Layer 2.
// Writes hs[i] = dis[i] * (A@W)[i]  (bf16), dis computed inline from cnt.
template<int MODE>
__global__ __launch_bounds__(256) void gemm_mfma_k(const float* __restrict__ A0,
                                                   const float* __restrict__ A1,
                                                   int nsplit,
                                                   const unsigned short* __restrict__ Ab,
                                                   const float* __restrict__ coefs,
                                                   const short* __restrict__ Wfrag,
                                                   const int* __restrict__ cntv,
                                                   unsigned short* __restrict__ hout) {
    __shared__ __align__(16) char smem[32768];       // full Wfrag

    int t    = threadIdx.x;
    int wave = t >> 6;           // 0..3
    int lane = t & 63;
    int kgrp = lane >> 4;        // 0..3
    int lrow = lane & 15;

    // ---- stage Wfrag into LDS (8 x 256 x 16B = 32KB, linear) ----
#pragma unroll
    for (int r = 0; r < 8; ++r) {
        const char* src = (const char*)Wfrag + (r * 256 + t) * 16;
        lds_u32* dst = (lds_u32*)(smem + (r * 256 + wave * 64) * 16);  // wave-uniform base
        __builtin_amdgcn_global_load_lds((glb_u32*)src, dst, 16, 0, 0);
    }

    // ---- A-row pointer (direct global) ----
    int row = blockIdx.x * 64 + wave * 16 + lrow;
    int lr = row > NN - 1 ? NN - 1 : row;
    const float* arow = nullptr;
    const unsigned short* brow = nullptr;
    if (MODE == 0) arow = (lr < nsplit) ? A0 + (size_t)lr * DD
                                        : A1 + (size_t)(lr - nsplit) * DD;
    else           brow = Ab + (size_t)lr * DD;
    float dv = rsqrtf((float)cntv[lr] + 1.0f);       // dis inline

    f32x4 acc[8];
#pragma unroll
    for (int ct = 0; ct < 8; ++ct) acc[ct] = (f32x4){0.f, 0.f, 0.f, 0.f};

    __syncthreads();   // Wfrag staged (drains vmcnt(0))

    const short8* wf = (const short8*)smem;

#pragma unroll
    for (int kk = 0; kk < 4; ++kk) {
        int d0 = kk * 32 + kgrp * 8;
        short8 rfrag;
        if (MODE == 0) {
            f32x4 va = *(const f32x4*)(arow + d0);
            f32x4 vb = *(const f32x4*)(arow + d0 + 4);
#pragma unroll
            for (int j = 0; j < 4; ++j) { rfrag[j] = f2bf(va[j]); rfrag[4 + j] = f2bf(vb[j]); }
        } else {
            ushort8 u = *(const ushort8*)(brow + d0);
            f32x4 s1 = *(const f32x4*)(coefs + d0);
            f32x4 s2 = *(const f32x4*)(coefs + d0 + 4);
            f32x4 t1 = *(const f32x4*)(coefs + 128 + d0);
            f32x4 t2 = *(const f32x4*)(coefs + 128 + d0 + 4);
#pragma unroll
            for (int j = 0; j < 4; ++j) {
                rfrag[j]     = f2bf(fmaxf(bf2f(u[j])     * s1[j] + t1[j], 0.f));
                rfrag[4 + j] = f2bf(fmaxf(bf2f(u[4 + j]) * s2[j] + t2[j], 0.f));
            }
        }
#pragma unroll
        for (int ct = 0; ct < 8; ++ct) {
            short8 wfr = wf[(ct * 4 + kk) * 64 + lane];   // contiguous ds_read_b128
            acc[ct] = __builtin_amdgcn_mfma_f32_16x16x32_bf16(wfr, rfrag, acc[ct], 0, 0, 0);
        }
    }

    // D layout (swapped operands): lane holds row fixed, cols ct*16+kgrp*4+j.
    // Pre-scale by dis[row] before bf16 pack.
    if (row < NN) {
        size_t rb = (size_t)row * DD;
#pragma unroll
        for (int ct = 0; ct < 8; ++ct) {
            int col = ct * 16 + kgrp * 4;
            unsigned p0 = (unsigned)(unsigned short)f2bf(acc[ct][0] * dv)
                        | ((unsigned)(unsigned short)f2bf(acc[ct][1] * dv) << 16);
            unsigned p1 = (unsigned)(unsigned short)f2bf(acc[ct][2] * dv)
                        | ((unsigned)(unsigned short)f2bf(acc[ct][3] * dv) << 16);
            uint2 p; p.x = p0; p.y = p1;
            *(uint2*)(hout + rb + col) = p;
        }
    }
}

// ---------------- unweighted gather + fused BN stats ----------------
// agg[i] = dis[i] * (sum_{s in N(i)} hs[s] + hs[i]) — hs is pre-scaled.
// dis[i] computed inline from cnt[row] (already loaded for the loop bound).
// PRUNE=1: store agg row only if flags[row] (rated); stats always from regs.
template<int PRUNE>
__global__ __launch_bounds__(256) void gather_k(const unsigned short* __restrict__ h,
                                                const int* __restrict__ sedge,
                                                const int* __restrict__ cnt,
                                                const unsigned char* __restrict__ flags,
                                                unsigned short* __restrict__ aggb,
                                                float* __restrict__ sums) {
    int t = threadIdx.x;
    int l = t & 15;                       // col octet index (8 cols each)
    int rg = t >> 4;                      // row within block
    int row = blockIdx.x * 16 + rg;
    int deg = cnt[row];
    int len = min(deg, ESTRIDE);
    const int* se = sedge + (size_t)row * ESTRIDE;
    const ushort8* hp = (const ushort8*)h;

    float acc[8];
#pragma unroll
    for (int j = 0; j < 8; ++j) acc[j] = 0.f;

    for (int base = 0; base < len; base += 4) {
        int i1 = min(base + 1, len - 1);
        int i2 = min(base + 2, len - 1);
        int i3 = min(base + 3, len - 1);
        int s0 = se[base], s1 = se[i1], s2 = se[i2], s3 = se[i3];
        ushort8 h0 = hp[(size_t)s0 * 16 + l];
        ushort8 h1 = hp[(size_t)s1 * 16 + l];
        ushort8 h2 = hp[(size_t)s2 * 16 + l];
        ushort8 h3 = hp[(size_t)s3 * 16 + l];
        float w1 = (base + 1 < len) ? 1.f : 0.f;     // tail-dup masks
        float w2 = (base + 2 < len) ? 1.f : 0.f;
        float w3 = (base + 3 < len) ? 1.f : 0.f;
#pragma unroll
        for (int j = 0; j < 8; ++j) {
            acc[j] += bf2f(h0[j]) + w1 * bf2f(h1[j])
                    + w2 * bf2f(h2[j]) + w3 * bf2f(h3[j]);
        }
    }
    float d = rsqrtf((float)deg + 1.0f);             // dis inline
    ushort8 hs = hp[(size_t)row * 16 + l];
    float r[8];
    ushort8 o;
#pragma unroll
    for (int j = 0; j < 8; ++j) {
        r[j] = d * (acc[j] + bf2f(hs[j]));
        o[j] = (unsigned short)f2bf(r[j]);
    }
    if (!PRUNE || flags[row])
        ((ushort8*)aggb)[(size_t)row * 16 + l] = o;

    // fused BN stats: block-local column reduction (odd stride), atomics
    __shared__ float red[16][129];
    float* slice = sums + (blockIdx.x & (NSLICE - 1)) * 256;
    int co = l * 8;
#pragma unroll
    for (int j = 0; j < 8; ++j) red[rg][co + j] = r[j];
    __syncthreads();
    if (t < 128) {
        float a = 0.f;
#pragma unroll
        for (int g = 0; g < 16; ++g) a += red[g][t];
        atomicAdd(&slice[t], a);
    }
    __syncthreads();
#pragma unroll
    for (int j = 0; j < 8; ++j) red[rg][co + j] = r[j] * r[j];
    __syncthreads();
    if (t < 128) {
        float a = 0.f;
#pragma unroll
        for (int g = 0; g < 16; ++g) a += red[g][t];
        atomicAdd(&slice[128 + t], a);
    }
}

// ---------------- BN coefficients (reduce NSLICE slices) ----------------
__global__ void bncoef_k(const float* __restrict__ sums,
                         const float* __restrict__ gamma,
                         const float* __restrict__ beta,
                         float* __restrict__ coefs) {
    int c = threadIdx.x;
    if (c >= DD) return;
    float s = 0.f, s2 = 0.f;
#pragma unroll
    for (int g = 0; g < NSLICE; ++g) {
        s  += sums[g * 256 + c];
        s2 += sums[g * 256 + 128 + c];
    }
    const float n = (float)NN;
    float m  = s / n;
    float v  = s2 / n - m * m;
    float is = rsqrtf(v + 1e-5f);
    float sc = gamma[c] * is;
    coefs[c] = sc;
    coefs[128 + c] = beta[c] - m * sc;
}

// ---------------- ratings: wave per pair, BN2+relu inline (bf16 x) ----------
__global__ __launch_bounds__(256) void ratings_k(const unsigned short* __restrict__ x,
                                                 const int* __restrict__ srcn,
                                                 const int* __restrict__ dstn,
                                                 const float* __restrict__ coefs,
                                                 float* __restrict__ out) {
    int wid  = (blockIdx.x * 256 + threadIdx.x) >> 6;
    int lane = threadIdx.x & 63;
    if (wid >= BB) return;
    int u = srcn[wid], v = dstn[wid];
    const ushort2* xp = (const ushort2*)x;
    ushort2 a = xp[(size_t)u * 64 + lane];
    ushort2 b = xp[(size_t)v * 64 + lane];
    float2 sc = ((const float2*)coefs)[lane];
    float2 sh = ((const float2*)(coefs + 128))[lane];
    float ax = fmaxf(bf2f(a.x) * sc.x + sh.x, 0.f);
    float ay = fmaxf(bf2f(a.y) * sc.y + sh.y, 0.f);
    float bx = fmaxf(bf2f(b.x) * sc.x + sh.x, 0.f);
    float by = fmaxf(bf2f(b.y) * sc.y + sh.y, 0.f);
    float acc = ax * bx + ay * by;
#pragma unroll
    for (int off = 32; off; off >>= 1) acc += __shfl_down(acc, off, 64);
    if (lane == 0) out[wid] = acc;
}

extern "C" void kernel_launch(void* const* d_in, const int* in_sizes, int n_in,
                              void* d_out, int out_size, void* d_ws, size_t ws_size,
                              hipStream_t stream) {
    const int*   edge  = (const int*)d_in[0];      // [2,E]
    const int*   esrc  = edge;
    const int*   edst  = edge + EE;
    const int*   srcn  = (const int*)d_in[2];
    const int*   dstn  = (const int*)d_in[3];
    const float* uemb  = (const float*)d_in[4];
    const float* bemb  = (const float*)d_in[5];
    const float* W1    = (const float*)d_in[6];
    // b1 = d_in[7]  (per-column constant, cancels in BN)
    const float* g1    = (const float*)d_in[8];
    const float* be1   = (const float*)d_in[9];
    const float* W2    = (const float*)d_in[10];
    // b2 = d_in[11] (cancels in BN)
    const float* g2    = (const float*)d_in[12];
    const float* be2   = (const float*)d_in[13];
    float* out = (float*)d_out;

    // workspace layout (16B-aligned; NN padded to 150016).
    // Zeroed range (contiguous): cnt, flags, sums1, sums2.
    unsigned short* aggb   = (unsigned short*)d_ws;                      // N*D bf16
    unsigned short* hbuf   = aggb + (size_t)NN * DD;                     // N*D bf16 (pre-scaled hs)
    int*            cnt    = (int*)(hbuf + (size_t)NN * DD);             // 150016
    unsigned char*  flags  = (unsigned char*)(cnt + 150016);             // 150016 bytes
    float*          sums1  = (float*)(flags + 150016);                   // NSLICE*256
    float*          sums2  = sums1 + NSLICE * 256;                       // NSLICE*256
    int*            sedge  = (int*)(sums2 + NSLICE * 256);               // 150016*16 int (9.6MB)
    short*          Wf1    = (short*)(sedge + (size_t)150016 * ESTRIDE); // 16384 bf16
    short*          Wf2    = Wf1 + 16384;                                // 16384 bf16
    float*          coef1  = (float*)(Wf2 + 16384);                      // 256
    float*          coef2  = coef1 + 256;                                // 256

    const int zn4   = (150016 * 4 + 150016 + 2 * NSLICE * 256 * 4) / 16; // 50976 int4
    const int zb    = (zn4 + 255) / 256;           // 200 zero blocks
    const int egrid = (EE + 255) / 256;            // 1954
    const int ggrid = (NN + 63) / 64;              // 2344 MFMA-GEMM blocks (64 rows, 256 thr)
    const int agrid = NN / 16;                     // 9375 gather blocks (exactly full)

    // ---- build: zero + Wfrag, fused count+fill+bitmap ----
    prep_k<<<zb + 128, 256, 0, stream>>>((int4*)cnt, zn4, zb, W1, W2, Wf1, Wf2);
    countfill_k<<<egrid, 256, 0, stream>>>(esrc, edst, cnt, sedge, srcn, dstn, flags);

    // ---- layer 1 ----
    gemm_mfma_k<0><<<ggrid, 256, 0, stream>>>(uemb, bemb, NUSERS, nullptr, nullptr, Wf1, cnt, hbuf);
    gather_k<0><<<agrid, 256, 0, stream>>>(hbuf, sedge, cnt, flags, aggb, sums1);
    bncoef_k<<<1, 128, 0, stream>>>(sums1, g1, be1, coef1);

    // ---- layer 2 (BN1+relu fused into GEMM A-load, bf16 A) ----
    gemm_mfma_k<1><<<ggrid, 256, 0, stream>>>(nullptr, nullptr, 0, aggb, coef1, Wf2, cnt, hbuf);
    gather_k<1><<<agrid, 256, 0, stream>>>(hbuf, sedge, cnt, flags, aggb, sums2);
    bncoef_k<<<1, 128, 0, stream>>>(sums2, g2, be2, coef2);

    // ---- ratings (BN2+relu inline) ----
    ratings_k<<<BB / 4, 256, 0, stream>>>(aggb, srcn, dstn, coef2, out);
}